// Round 1
// baseline (358.385 us; speedup 1.0000x reference)
//
#include <hip/hip_runtime.h>
#include <math.h>

// ArcFace head, B=131072, D=512, C=2.
// Memory-bound: 256 MB feat read dominates. Wave-per-row, float4 loads,
// shfl_xor reduction, trig-identity margin (no acos/cos).

#define D_DIM 512

__device__ __forceinline__ float dot4(const float4& a, const float4& b) {
    return a.x * b.x + a.y * b.y + a.z * b.z + a.w * b.w;
}

__global__ __launch_bounds__(256, 4) void arcface_kernel(
    const float* __restrict__ feat,
    const float* __restrict__ W,
    const int* __restrict__ label,
    float* __restrict__ out,
    int n_rows)
{
    const float EPS   = 1e-7f;
    const float COS_M = 0.87758256189037271612f;  // cos(0.5)
    const float SIN_M = 0.47942553860420300027f;  // sin(0.5)
    const float S     = 64.0f;

    __shared__ float s_inv[2];

    const int tid  = threadIdx.x;
    const int wave = tid >> 6;
    const int lane = tid & 63;

    // ---- Phase 1: waves 0/1 compute 1/||W_row|| (W is 2x512, L2-hot) ----
    if (wave < 2) {
        const float4* Wv = (const float4*)(W + wave * D_DIM);
        float4 a = Wv[lane];
        float4 b = Wv[64 + lane];
        float ss = dot4(a, a) + dot4(b, b);
        #pragma unroll
        for (int m = 32; m >= 1; m >>= 1) ss += __shfl_xor(ss, m);
        if (lane == 0) {
            s_inv[wave] = 1.0f / fmaxf(sqrtf(ss), 1e-12f);
        }
    }
    __syncthreads();
    const float invW0 = s_inv[0];
    const float invW1 = s_inv[1];

    // ---- Load this lane's W fragments into registers (reused all rows) ----
    const float4* W0v = (const float4*)W;
    const float4* W1v = (const float4*)(W + D_DIM);
    const float4 w00 = W0v[lane];       // W0 elems [lane*4, +4)
    const float4 w01 = W0v[64 + lane];  // W0 elems [256 + lane*4, +4)
    const float4 w10 = W1v[lane];
    const float4 w11 = W1v[64 + lane];

    // ---- Grid-stride loop: one wave per row ----
    const int gw      = blockIdx.x * 4 + wave;
    const int n_waves = gridDim.x * 4;

    for (int r = gw; r < n_rows; r += n_waves) {
        const float4* fv = (const float4*)(feat + (size_t)r * D_DIM);
        float4 f0 = fv[lane];       // coalesced: 64 lanes x 16B = 1 KB
        float4 f1 = fv[64 + lane];  // second contiguous 1 KB

        float d0 = dot4(f0, w00) + dot4(f1, w01);  // feat . W0
        float d1 = dot4(f0, w10) + dot4(f1, w11);  // feat . W1
        float nn = dot4(f0, f0)  + dot4(f1, f1);   // ||feat||^2

        #pragma unroll
        for (int m = 32; m >= 1; m >>= 1) {
            d0 += __shfl_xor(d0, m);
            d1 += __shfl_xor(d1, m);
            nn += __shfl_xor(nn, m);
        }

        if (lane == 0) {
            const float invF = 1.0f / fmaxf(sqrtf(nn), 1e-12f);
            float c0 = d0 * invF * invW0;
            float c1 = d1 * invF * invW1;
            c0 = fminf(fmaxf(c0, -1.0f + EPS), 1.0f - EPS);
            c1 = fminf(fmaxf(c1, -1.0f + EPS), 1.0f - EPS);
            // cos(theta + m) = c*cos(m) - sqrt(1-c^2)*sin(m), sin(theta)>=0
            const float m0 = c0 * COS_M - sqrtf(fmaxf(1.0f - c0 * c0, 0.0f)) * SIN_M;
            const float m1 = c1 * COS_M - sqrtf(fmaxf(1.0f - c1 * c1, 0.0f)) * SIN_M;
            const int lb = label[r];
            const float o0 = (lb == 0) ? m0 : c0;
            const float o1 = (lb == 1) ? m1 : c1;
            ((float2*)out)[r] = make_float2(o0 * S, o1 * S);
        }
    }
}

extern "C" void kernel_launch(void* const* d_in, const int* in_sizes, int n_in,
                              void* d_out, int out_size, void* d_ws, size_t ws_size,
                              hipStream_t stream) {
    const float* feat  = (const float*)d_in[0];
    const float* W     = (const float*)d_in[1];
    const int*   label = (const int*)d_in[2];
    float*       out   = (float*)d_out;

    const int n_rows = in_sizes[2];  // B = 131072

    const int blocks = 4096;  // 8192 waves -> 16 rows/wave grid-stride
    arcface_kernel<<<blocks, 256, 0, stream>>>(feat, W, label, out, n_rows);
}

// Round 2
// 357.250 us; speedup vs baseline: 1.0032x; 1.0032x over previous
//
#include <hip/hip_runtime.h>
#include <math.h>

// ArcFace head, B=131072, D=512, C=2. Memory-bound (256 MB feat stream).
// v2: 32 lanes per row (half-wave), 2 row-pairs unrolled -> 4 rows / wave
// in flight (8 KB MLP), 5-stage butterfly reduces both halves' rows with
// the same instructions (7.5 DS ops/row vs 18 in v1).

#define D_DIM 512

__device__ __forceinline__ float dot4(const float4& a, const float4& b) {
    return a.x * b.x + a.y * b.y + a.z * b.z + a.w * b.w;
}

__device__ __forceinline__ float4 scale4(const float4& a, float s) {
    return make_float4(a.x * s, a.y * s, a.z * s, a.w * s);
}

__global__ __launch_bounds__(256, 4) void arcface_kernel(
    const float* __restrict__ feat,
    const float* __restrict__ W,
    const int* __restrict__ label,
    float* __restrict__ out,
    int n_rows)
{
    const float EPS   = 1e-7f;
    const float COS_M = 0.87758256189037271612f;  // cos(0.5)
    const float SIN_M = 0.47942553860420300027f;  // sin(0.5)
    const float S     = 64.0f;

    const int tid  = threadIdx.x;
    const int wave = tid >> 6;
    const int lane = tid & 63;
    const int l32  = lane & 31;   // lane within half-wave (row group)

    // ---- W fragments: each lane covers 16 elems of each W row ----
    const float4* W0v = (const float4*)W;
    const float4* W1v = (const float4*)(W + D_DIM);
    float4 w0[4], w1[4];
    #pragma unroll
    for (int k = 0; k < 4; k++) {
        w0[k] = W0v[l32 + 32 * k];
        w1[k] = W1v[l32 + 32 * k];
    }

    // ---- W norms: 5-stage butterfly within each 32-lane half ----
    float ss0 = 0.f, ss1 = 0.f;
    #pragma unroll
    for (int k = 0; k < 4; k++) {
        ss0 += dot4(w0[k], w0[k]);
        ss1 += dot4(w1[k], w1[k]);
    }
    #pragma unroll
    for (int m = 16; m >= 1; m >>= 1) {
        ss0 += __shfl_xor(ss0, m);
        ss1 += __shfl_xor(ss1, m);
    }
    const float inv0 = 1.0f / fmaxf(sqrtf(ss0), 1e-12f);
    const float inv1 = 1.0f / fmaxf(sqrtf(ss1), 1e-12f);
    #pragma unroll
    for (int k = 0; k < 4; k++) {       // fold 1/||W|| into fragments
        w0[k] = scale4(w0[k], inv0);
        w1[k] = scale4(w1[k], inv1);
    }

    // ---- half-wave id: one row per half-wave per unroll slot ----
    const int hw  = (blockIdx.x * 4 + wave) * 2 + (lane >> 5);
    const int nhw = gridDim.x * 8;       // total half-waves

    for (int r = hw; r < n_rows; r += 2 * nhw) {
        const int  rA   = r;
        const int  rB   = r + nhw;
        const bool hasB = (rB < n_rows);

        // Issue all 8 loads (8 KB/wave) before any use.
        const float4* fA = (const float4*)(feat + (size_t)rA * D_DIM);
        const float4* fB = (const float4*)(feat + (size_t)(hasB ? rB : rA) * D_DIM);
        float4 a[4], b[4];
        #pragma unroll
        for (int k = 0; k < 4; k++) a[k] = fA[l32 + 32 * k];
        #pragma unroll
        for (int k = 0; k < 4; k++) b[k] = fB[l32 + 32 * k];

        float d0A = 0.f, d1A = 0.f, nnA = 0.f;
        float d0B = 0.f, d1B = 0.f, nnB = 0.f;
        #pragma unroll
        for (int k = 0; k < 4; k++) {
            d0A += dot4(a[k], w0[k]);  d1A += dot4(a[k], w1[k]);  nnA += dot4(a[k], a[k]);
            d0B += dot4(b[k], w0[k]);  d1B += dot4(b[k], w1[k]);  nnB += dot4(b[k], b[k]);
        }

        // 5-stage butterfly: each half reduces its own row in parallel.
        #pragma unroll
        for (int m = 16; m >= 1; m >>= 1) {
            d0A += __shfl_xor(d0A, m);  d1A += __shfl_xor(d1A, m);  nnA += __shfl_xor(nnA, m);
            d0B += __shfl_xor(d0B, m);  d1B += __shfl_xor(d1B, m);  nnB += __shfl_xor(nnB, m);
        }

        if (l32 == 0) {
            {   // row A
                const float invF = 1.0f / fmaxf(sqrtf(nnA), 1e-12f);
                float c0 = fminf(fmaxf(d0A * invF, -1.0f + EPS), 1.0f - EPS);
                float c1 = fminf(fmaxf(d1A * invF, -1.0f + EPS), 1.0f - EPS);
                const float m0 = c0 * COS_M - sqrtf(fmaxf(1.0f - c0 * c0, 0.0f)) * SIN_M;
                const float m1 = c1 * COS_M - sqrtf(fmaxf(1.0f - c1 * c1, 0.0f)) * SIN_M;
                const int lb = label[rA];
                ((float2*)out)[rA] = make_float2(((lb == 0) ? m0 : c0) * S,
                                                 ((lb == 1) ? m1 : c1) * S);
            }
            if (hasB) {  // row B
                const float invF = 1.0f / fmaxf(sqrtf(nnB), 1e-12f);
                float c0 = fminf(fmaxf(d0B * invF, -1.0f + EPS), 1.0f - EPS);
                float c1 = fminf(fmaxf(d1B * invF, -1.0f + EPS), 1.0f - EPS);
                const float m0 = c0 * COS_M - sqrtf(fmaxf(1.0f - c0 * c0, 0.0f)) * SIN_M;
                const float m1 = c1 * COS_M - sqrtf(fmaxf(1.0f - c1 * c1, 0.0f)) * SIN_M;
                const int lb = label[rB];
                ((float2*)out)[rB] = make_float2(((lb == 0) ? m0 : c0) * S,
                                                 ((lb == 1) ? m1 : c1) * S);
            }
        }
    }
}

extern "C" void kernel_launch(void* const* d_in, const int* in_sizes, int n_in,
                              void* d_out, int out_size, void* d_ws, size_t ws_size,
                              hipStream_t stream) {
    const float* feat  = (const float*)d_in[0];
    const float* W     = (const float*)d_in[1];
    const int*   label = (const int*)d_in[2];
    float*       out   = (float*)d_out;

    const int n_rows = in_sizes[2];  // B = 131072

    // 4096 blocks -> 32768 half-waves -> 4 rows/half-wave (2 unrolled iters)
    const int blocks = 4096;
    arcface_kernel<<<blocks, 256, 0, stream>>>(feat, W, label, out, n_rows);
}